// Round 1
// baseline (207.800 us; speedup 1.0000x reference)
//
#include <hip/hip_runtime.h>
#include <cmath>

// Problem constants: bs=16, l=128, d=256
constexpr int D    = 256;
constexpr int LSEQ = 128;
constexpr int BSZ  = 16;
constexpr int MROW = BSZ * LSEQ;   // 2048

// GEMM: out[r,e] = sum_k A[r,k] * W[e,k]  (+ bias[e] | + c[b,e]), optional row mask on A.
// A: MROW x 256 row-major. W: rows stride ldw. Tile 64x64, BK=32, 256 thr, 4x4/thread.
__global__ __launch_bounds__(256) void gemm_k(
    const float* __restrict__ A, const float* __restrict__ W, int ldw,
    const float* __restrict__ addv, const float* __restrict__ mask,
    float* __restrict__ out, int mode)   // mode 0: +addv[e]; 1: none; 2: +addv[(r>>7)*256+e]
{
    __shared__ float As[32][68];   // k-major, stride 68 floats (16B aligned, conflict-light)
    __shared__ float Bs[32][68];
    const int tid = threadIdx.x;
    const int tx = tid & 15, ty = tid >> 4;
    const int r0 = blockIdx.x * 64, e0 = blockIdx.y * 64;

    float acc[4][4] = {};

    for (int k0 = 0; k0 < D; k0 += 32) {
        #pragma unroll
        for (int t = tid; t < 512; t += 256) {
            int row = t >> 3, kk = (t & 7) << 2;
            float4 v = *(const float4*)(A + (long)(r0 + row) * D + k0 + kk);
            if (mask) { float mv = mask[r0 + row]; v.x *= mv; v.y *= mv; v.z *= mv; v.w *= mv; }
            As[kk + 0][row] = v.x; As[kk + 1][row] = v.y;
            As[kk + 2][row] = v.z; As[kk + 3][row] = v.w;
        }
        #pragma unroll
        for (int t = tid; t < 512; t += 256) {
            int row = t >> 3, kk = (t & 7) << 2;
            float4 v = *(const float4*)(W + (long)(e0 + row) * ldw + k0 + kk);
            Bs[kk + 0][row] = v.x; Bs[kk + 1][row] = v.y;
            Bs[kk + 2][row] = v.z; Bs[kk + 3][row] = v.w;
        }
        __syncthreads();
        #pragma unroll
        for (int kk = 0; kk < 32; ++kk) {
            float4 av = *(const float4*)&As[kk][ty << 2];
            float4 bv = *(const float4*)&Bs[kk][tx << 2];
            float a[4] = {av.x, av.y, av.z, av.w};
            float b[4] = {bv.x, bv.y, bv.z, bv.w};
            #pragma unroll
            for (int i = 0; i < 4; ++i)
                #pragma unroll
                for (int j = 0; j < 4; ++j)
                    acc[i][j] = fmaf(a[i], b[j], acc[i][j]);
        }
        __syncthreads();
    }

    #pragma unroll
    for (int i = 0; i < 4; ++i) {
        int r = r0 + (ty << 2) + i;
        #pragma unroll
        for (int j = 0; j < 4; ++j) {
            int e = e0 + (tx << 2) + j;
            float v = acc[i][j];
            if (mode == 0)      v += addv[e];
            else if (mode == 2) v += addv[(r >> 7) * D + e];
            out[(long)r * D + e] = v;
        }
    }
}

// Online-softmax partial stats over a 32-row i-quarter.
// grid (16, 4), block 256 (one thread per e). Coalesced row reads.
__global__ __launch_bounds__(256) void stats_k(
    const float* __restrict__ s1, const float* __restrict__ xhid,
    float* __restrict__ pm, float* __restrict__ pz, float* __restrict__ pa)
{
    const int b = blockIdx.x, iq = blockIdx.y, e = threadIdx.x;
    const long base = ((long)b * LSEQ + iq * 32) * D + e;
    float m = -1e30f, z = 0.f, a = 0.f;
    #pragma unroll 4
    for (int i = 0; i < 32; ++i) {
        float s = s1[base + (long)i * D];
        float x = xhid[base + (long)i * D];
        float mn = fmaxf(m, s);
        float sc = __expf(m - mn);
        float p  = __expf(s - mn);
        z = z * sc + p;
        a = a * sc + p * x;
        m = mn;
    }
    int idx = (b * 4 + iq) * D + e;
    pm[idx] = m; pz[idx] = z; pa[idx] = a;
}

// Merge 4 partials -> agg = sigmoid(A/Z); then c[b,e'] = agg . upd_w[e',256:] + upd_b[e'].
// grid 16, block 256.
__global__ __launch_bounds__(256) void cvec_k(
    const float* __restrict__ pm, const float* __restrict__ pz, const float* __restrict__ pa,
    const float* __restrict__ updw, const float* __restrict__ updb,
    float* __restrict__ cvec)
{
    const int b = blockIdx.x, e = threadIdx.x;
    __shared__ float aggs[D];
    float m = -1e30f, z = 0.f, a = 0.f;
    #pragma unroll
    for (int q = 0; q < 4; ++q) {
        int idx = (b * 4 + q) * D + e;
        float mq = pm[idx], zq = pz[idx], aq = pa[idx];
        float mn = fmaxf(m, mq);
        float s0 = __expf(m - mn), s1e = __expf(mq - mn);
        z = z * s0 + zq * s1e;
        a = a * s0 + aq * s1e;
        m = mn;
    }
    aggs[e] = 1.f / (1.f + __expf(-(a / z)));
    __syncthreads();
    float c = updb[e];
    const float* wrow = updw + (long)e * 512 + 256;
    #pragma unroll 8
    for (int d0 = 0; d0 < D; d0 += 4) {
        float4 wv = *(const float4*)(wrow + d0);
        c += aggs[d0 + 0] * wv.x + aggs[d0 + 1] * wv.y
           + aggs[d0 + 2] * wv.z + aggs[d0 + 3] * wv.w;
    }
    cvec[b * D + e] = c;
}

extern "C" void kernel_launch(void* const* d_in, const int* in_sizes, int n_in,
                              void* d_out, int out_size, void* d_ws, size_t ws_size,
                              hipStream_t stream) {
    const float* feat   = (const float*)d_in[0];
    const float* mask   = (const float*)d_in[1];
    const float* agg_w  = (const float*)d_in[2];
    const float* agg_b  = (const float*)d_in[3];
    const float* attn_w = (const float*)d_in[4];  // W1 = rows, cols 0..255 (attn_b cancels)
    const float* upd_w  = (const float*)d_in[6];
    const float* upd_b  = (const float*)d_in[7];
    float* out = (float*)d_out;

    float* xhid = (float*)d_ws;            // 2048*256
    float* s1b  = xhid + MROW * D;         // 2048*256
    float* hidA = s1b + MROW * D;          // 2048*256
    float* pm   = hidA + MROW * D;         // 16*4*256
    float* pz   = pm + BSZ * 4 * D;
    float* pa   = pz + BSZ * 4 * D;
    float* cv   = pa + BSZ * 4 * D;        // 16*256

    dim3 gg(MROW / 64, D / 64);            // 32 x 4 = 128 blocks

    const float* hin = feat;
    float* houts[3] = { hidA, out, out };  // feat -> hidA -> out -> out

    for (int st = 0; st < 3; ++st) {
        // xhid = (hid * mask) @ agg_w^T + agg_b
        gemm_k<<<gg, 256, 0, stream>>>(hin, agg_w, D, agg_b, mask, xhid, 0);
        // s1 = xhid @ W1^T   (W1 = attn_w[:, :256], row stride 512)
        gemm_k<<<gg, 256, 0, stream>>>(xhid, attn_w, 512, nullptr, nullptr, s1b, 1);
        // softmax-over-i partial stats (per b, i-quarter, e)
        stats_k<<<dim3(BSZ, 4), 256, 0, stream>>>(s1b, xhid, pm, pz, pa);
        // merge + agg + c vector
        cvec_k<<<BSZ, 256, 0, stream>>>(pm, pz, pa, upd_w, upd_b, cv);
        // hid' = xhid @ upd_w[:, :256]^T + c[b,:]
        gemm_k<<<gg, 256, 0, stream>>>(xhid, upd_w, 512, cv, nullptr, houts[st], 2);
        hin = houts[st];
    }
}

// Round 2
// 165.956 us; speedup vs baseline: 1.2521x; 1.2521x over previous
//
#include <hip/hip_runtime.h>
#include <cmath>

constexpr int D    = 256;
constexpr int MROW = 2048;   // 16 batches * 128 rows

// ---------------------------------------------------------------------------
// prep: build packed weight layouts (one dispatch, off critical path)
//  wt12[k][e]      = attn_w[e][k]                (e<256)   -- W1^T
//  wt12[k][256+e]  = M1[e][k],  M1 = agg_w @ U1            -- (agg_w.U1)^T
//  wt3 [k][e]      = attn_w[e][k]                          -- W1^T
//  wt3 [k][256+e]  = upd_w[e][k]                           -- U1^T
//  awt [k][e]      = agg_w[e][k]                           -- agg_w^T
//  u2t [d][e]      = upd_w[e][256+d]                       -- U2^T
// ---------------------------------------------------------------------------
__global__ __launch_bounds__(256) void prep_k(
    const float* __restrict__ agg_w, const float* __restrict__ attn_w,
    const float* __restrict__ upd_w,
    float* __restrict__ wt12, float* __restrict__ wt3,
    float* __restrict__ awt,  float* __restrict__ u2t)
{
    const int bx = blockIdx.x, t = threadIdx.x;
    if (bx < 64) {
        // M1[e,f] = sum_d agg_w[e,d] * upd_w[d*512 + f], e in [4bx, 4bx+4)
        __shared__ float agL[4][256];
        const int e0 = bx * 4;
        {
            int row = t >> 6, d0 = (t & 63) * 4;
            *(float4*)&agL[row][d0] = *(const float4*)(agg_w + (e0 + row) * 256 + d0);
        }
        __syncthreads();
        float acc[4] = {0.f, 0.f, 0.f, 0.f};
        #pragma unroll 4
        for (int d = 0; d < 256; ++d) {
            float u = upd_w[d * 512 + t];
            acc[0] = fmaf(agL[0][d], u, acc[0]);
            acc[1] = fmaf(agL[1][d], u, acc[1]);
            acc[2] = fmaf(agL[2][d], u, acc[2]);
            acc[3] = fmaf(agL[3][d], u, acc[3]);
        }
        #pragma unroll
        for (int i = 0; i < 4; ++i)
            wt12[t * 512 + 256 + e0 + i] = acc[i];   // wt12[k=t? no: row t][...] -- see note
    } else {
        const int kg = bx - 64;                      // 0..15
        #pragma unroll 2
        for (int j = 0; j < 16; ++j) {
            int k = kg * 16 + j;
            wt12[k * 512 + t]       = attn_w[t * 512 + k];
            wt3 [k * 512 + t]       = attn_w[t * 512 + k];
            wt3 [k * 512 + 256 + t] = upd_w[t * 512 + k];
            awt [k * 256 + t]       = agg_w[t * 256 + k];
            u2t [k * 256 + t]       = upd_w[t * 512 + 256 + k];
        }
    }
}
// note: in the bx<64 branch, thread t computes M1[e0+i][f=t] and stores it at
// wt12[f*512 + 256 + e], i.e. row index = f (the k role), exactly wt12[k][256+e]=M1[e][k].

// ---------------------------------------------------------------------------
// Fused GEMM: out[r, c] = sum_k A'[r,k] * Wt[k, c0+c],  16 rows x 128 cols / block
//   AMODE 0: A' = Asrc                       (plain)
//   AMODE 1: A' = Asrc * mask[r]             (step-1 feat)
//   AMODE 2: A' = mask[r]*(Asrc + cA[b]) + agg_b   (fold prev-step epilogue)
//   EPI 0: write acc + bias[e] to gout (N=256)            -- G0
//   EPI 1: by<2 -> softmax partial stats from acc + A_lds; by>=2 -> write G2
// 4 waves; wave = 4 rows x 128 cols; lane -> col pair. A in LDS (wave-uniform
// broadcast reads); W streamed global->reg, k-blocked by 4.
// ---------------------------------------------------------------------------
template<int AMODE, int EPI>
__global__ __launch_bounds__(256) void gemm_k(
    const float* __restrict__ Asrc, const float* __restrict__ Wt, int wld,
    const float* __restrict__ maskp, const float* __restrict__ cA,
    const float* __restrict__ aggb,
    float* __restrict__ gout,
    float* __restrict__ pm, float* __restrict__ pz, float* __restrict__ pa)
{
    __shared__ float As[16][260];
    const int t    = threadIdx.x;
    const int lane = t & 63, wv = t >> 6;
    const int bx = blockIdx.x, by = blockIdx.y;
    const int r0 = bx * 16;
    const int c0 = by * 128;
    const int b  = r0 >> 7;

    // ---- stage (and transform) A: 16 x 256 -> LDS ----
    {
        int row = t >> 4;
        int k4  = (t & 15) * 16;
        const float* src = Asrc + (size_t)(r0 + row) * 256 + k4;
        float mv = (AMODE != 0) ? maskp[r0 + row] : 1.f;
        #pragma unroll
        for (int j = 0; j < 4; ++j) {
            float4 v = *(const float4*)(src + 4 * j);
            if (AMODE == 1) { v.x *= mv; v.y *= mv; v.z *= mv; v.w *= mv; }
            if (AMODE == 2) {
                float4 c4 = *(const float4*)(cA + b * 256 + k4 + 4 * j);
                float4 a4 = *(const float4*)(aggb + k4 + 4 * j);
                v.x = fmaf(mv, v.x + c4.x, a4.x);
                v.y = fmaf(mv, v.y + c4.y, a4.y);
                v.z = fmaf(mv, v.z + c4.z, a4.z);
                v.w = fmaf(mv, v.w + c4.w, a4.w);
            }
            *(float4*)&As[row][k4 + 4 * j] = v;
        }
    }
    __syncthreads();

    // ---- main loop ----
    float acc[4][2] = {};
    const float* wp = Wt + c0 + 2 * lane;
    const int rw = wv * 4;

    #pragma unroll 4
    for (int kq = 0; kq < 64; ++kq) {
        float2 w0 = *(const float2*)(wp);
        float2 w1 = *(const float2*)(wp + wld);
        float2 w2 = *(const float2*)(wp + 2 * wld);
        float2 w3 = *(const float2*)(wp + 3 * wld);
        wp += 4 * wld;
        const int k = kq * 4;
        float4 a0 = *(const float4*)&As[rw + 0][k];
        float4 a1 = *(const float4*)&As[rw + 1][k];
        float4 a2 = *(const float4*)&As[rw + 2][k];
        float4 a3 = *(const float4*)&As[rw + 3][k];
        #define ROWSTEP(r, ar)                                                      \
            acc[r][0] = fmaf(ar.x, w0.x, fmaf(ar.y, w1.x,                           \
                        fmaf(ar.z, w2.x, fmaf(ar.w, w3.x, acc[r][0]))));            \
            acc[r][1] = fmaf(ar.x, w0.y, fmaf(ar.y, w1.y,                           \
                        fmaf(ar.z, w2.y, fmaf(ar.w, w3.y, acc[r][1]))));
        ROWSTEP(0, a0) ROWSTEP(1, a1) ROWSTEP(2, a2) ROWSTEP(3, a3)
        #undef ROWSTEP
    }

    // ---- epilogue ----
    if (EPI == 0) {
        const int e = c0 + 2 * lane;
        float2 bias = *(const float2*)(aggb + e);
        #pragma unroll
        for (int r = 0; r < 4; ++r) {
            float2 v = { acc[r][0] + bias.x, acc[r][1] + bias.y };
            *(float2*)(gout + (size_t)(r0 + rw + r) * 256 + e) = v;
        }
    } else {
        if (by < 2) {
            // softmax partial stats over this wave's 4 rows (s1 half, e<256)
            const int gg = bx * 4 + wv;       // 4-row group id (row/4)
            const int e  = c0 + 2 * lane;
            float pmA[2], pzA[2], paA[2];
            #pragma unroll
            for (int c = 0; c < 2; ++c) {
                float s0 = acc[0][c], s1 = acc[1][c], s2 = acc[2][c], s3 = acc[3][c];
                float m  = fmaxf(fmaxf(s0, s1), fmaxf(s2, s3));
                float p0 = __expf(s0 - m), p1 = __expf(s1 - m);
                float p2 = __expf(s2 - m), p3 = __expf(s3 - m);
                const int ee = e + c;         // == k index of xhid column
                float a = p0 * As[rw + 0][ee] + p1 * As[rw + 1][ee]
                        + p2 * As[rw + 2][ee] + p3 * As[rw + 3][ee];
                pmA[c] = m; pzA[c] = p0 + p1 + p2 + p3; paA[c] = a;
            }
            *(float2*)(pm + gg * 256 + e) = make_float2(pmA[0], pmA[1]);
            *(float2*)(pz + gg * 256 + e) = make_float2(pzA[0], pzA[1]);
            *(float2*)(pa + gg * 256 + e) = make_float2(paA[0], paA[1]);
        } else {
            const int e = c0 - 256 + 2 * lane;
            #pragma unroll
            for (int r = 0; r < 4; ++r) {
                float2 v = { acc[r][0], acc[r][1] };
                *(float2*)(gout + (size_t)(r0 + rw + r) * 256 + e) = v;
            }
        }
    }
}

// ---------------------------------------------------------------------------
// CK: merge 32 4-row partials per batch -> agg -> c[e].
//   MODE 0: also cA[b,e] = sum_d c[d]*awt[d][e]; write cA   (grid 16)
//   MODE 1: out[r,e] = g2[r,e] + c[e] for 16-row slice      (grid 16 x 8)
// ---------------------------------------------------------------------------
template<int MODE>
__global__ __launch_bounds__(256) void ck_k(
    const float* __restrict__ pm, const float* __restrict__ pz,
    const float* __restrict__ pa,
    const float* __restrict__ u2t, const float* __restrict__ updb,
    const float* __restrict__ awt,
    const float* __restrict__ g2, float* __restrict__ outp)
{
    const int b = blockIdx.x, e = threadIdx.x;
    float m = -1e30f, z = 0.f, a = 0.f;
    #pragma unroll 4
    for (int g = 0; g < 32; ++g) {
        int idx = (b * 32 + g) * 256 + e;
        float mq = pm[idx], zq = pz[idx], aq = pa[idx];
        float mn = fmaxf(m, mq);
        float sA = __expf(m - mn), sB = __expf(mq - mn);
        z = z * sA + zq * sB;
        a = a * sA + aq * sB;
        m = mn;
    }
    __shared__ float aggs[256];
    __shared__ float cs[256];
    aggs[e] = 1.f / (1.f + __expf(-(a / z)));
    __syncthreads();
    float c = updb[e];
    #pragma unroll 8
    for (int d = 0; d < 256; ++d)
        c = fmaf(aggs[d], u2t[d * 256 + e], c);
    if (MODE == 0) {
        cs[e] = c;
        __syncthreads();
        float ca = 0.f;
        #pragma unroll 8
        for (int d = 0; d < 256; ++d)
            ca = fmaf(cs[d], awt[d * 256 + e], ca);
        outp[b * 256 + e] = ca;
    } else {
        const int r0 = b * 128 + blockIdx.y * 16;
        #pragma unroll 4
        for (int r = 0; r < 16; ++r) {
            size_t off = (size_t)(r0 + r) * 256 + e;
            outp[off] = g2[off] + c;
        }
    }
}

// ---------------------------------------------------------------------------
extern "C" void kernel_launch(void* const* d_in, const int* in_sizes, int n_in,
                              void* d_out, int out_size, void* d_ws, size_t ws_size,
                              hipStream_t stream) {
    const float* feat   = (const float*)d_in[0];
    const float* mask   = (const float*)d_in[1];
    const float* agg_w  = (const float*)d_in[2];
    const float* agg_b  = (const float*)d_in[3];
    const float* attn_w = (const float*)d_in[4];   // attn_b (d_in[5]) cancels in softmax
    const float* upd_w  = (const float*)d_in[6];
    const float* upd_b  = (const float*)d_in[7];
    float* out = (float*)d_out;

    float* p    = (float*)d_ws;
    float* wt12 = p; p += 256 * 512;
    float* wt3  = p; p += 256 * 512;
    float* awt  = p; p += 256 * 256;
    float* u2t  = p; p += 256 * 256;
    float* buf0 = p; p += MROW * D;
    float* buf1 = p; p += MROW * D;
    float* pm   = p; p += 512 * 256;
    float* pz   = p; p += 512 * 256;
    float* pa   = p; p += 512 * 256;
    float* cA   = p; p += 16 * 256;

    prep_k<<<80, 256, 0, stream>>>(agg_w, attn_w, upd_w, wt12, wt3, awt, u2t);

    // G0: xhid_1 = (feat*mask) @ agg_w^T + agg_b            -> buf0
    gemm_k<1, 0><<<dim3(128, 2), 256, 0, stream>>>(
        feat, awt, 256, mask, nullptr, agg_b, buf0, nullptr, nullptr, nullptr);

    // BIG1: [s1_1 | G2_1] = xhid_1 @ [W1|M1]^T ; stats ; G2 -> buf1
    gemm_k<0, 1><<<dim3(128, 4), 256, 0, stream>>>(
        buf0, wt12, 512, nullptr, nullptr, nullptr, buf1, pm, pz, pa);
    ck_k<0><<<16, 256, 0, stream>>>(pm, pz, pa, u2t, upd_b, awt, nullptr, cA);

    // BIG2: A = m*(G2_1 + cA_1) + agg_b (== xhid_2); G2_2 -> buf0
    gemm_k<2, 1><<<dim3(128, 4), 256, 0, stream>>>(
        buf1, wt12, 512, mask, cA, agg_b, buf0, pm, pz, pa);
    ck_k<0><<<16, 256, 0, stream>>>(pm, pz, pa, u2t, upd_b, awt, nullptr, cA);

    // BIG3: A = xhid_3; right half uses U1^T -> G2_3 = xhid_3 @ U1^T -> buf1
    gemm_k<2, 1><<<dim3(128, 4), 256, 0, stream>>>(
        buf0, wt3, 512, mask, cA, agg_b, buf1, pm, pz, pa);

    // out = G2_3 + c_3
    ck_k<1><<<dim3(16, 8), 256, 0, stream>>>(pm, pz, pa, u2t, upd_b, awt, buf1, out);
}